// Round 13
// baseline (91.363 us; speedup 1.0000x reference)
//
#include <hip/hip_runtime.h>
#include <hip/hip_bf16.h>

// Problem constants
#define NB   256
#define NC   4096
#define NG   512
#define NH   128
#define NELEM (NB*NC)            // 1048576
#define LDX  66                  // row stride of x_with_meta in floats
#define NEGV (-1000000000.0f)
#define TILES 16                 // 128-row tiles per block
#define TILE_ROWS 128
#define GRID_MLP (NELEM/(TILES*TILE_ROWS))   // 512 = 2 blocks/CU exactly, 1 round

typedef __attribute__((ext_vector_type(8))) short short8;
typedef __attribute__((ext_vector_type(4))) float f32x4;

// truncating f32->bf16 pair pack
__device__ __forceinline__ unsigned pack2(float x, float y) {
    return (__float_as_uint(y) & 0xFFFF0000u) | (__float_as_uint(x) >> 16);
}
__device__ __forceinline__ unsigned short f2bf(float f) {   // RNE, off hot path
    unsigned u = __float_as_uint(f);
    return (unsigned short)((u + 0x7FFFu + ((u >> 16) & 1u)) >> 16);
}
__device__ __forceinline__ unsigned char f2fp8(float f) {   // e4m3, off hot path
    return (unsigned char)((unsigned)__builtin_amdgcn_cvt_pk_fp8_f32(f, 0.f, 0, false) & 0xFFu);
}
__device__ __forceinline__ unsigned encf(float f) {         // order-preserving f32->u32
    unsigned u = __float_as_uint(f);
    return (u & 0x80000000u) ? ~u : (u | 0x80000000u);
}
__device__ __forceinline__ float decf(unsigned u) {
    unsigned v = (u & 0x80000000u) ? (u ^ 0x80000000u) : ~u;
    return __uint_as_float(v);
}
__device__ __forceinline__ f32x4 mfma_bf16(short8 a, short8 b, f32x4 c) {
    return __builtin_amdgcn_mfma_f32_16x16x32_bf16(a, b, c, 0, 0, 0);
}
__device__ __forceinline__ f32x4 mfma_fp8(long a, long b, f32x4 c) {
    return __builtin_amdgcn_mfma_f32_16x16x32_fp8_fp8(a, b, c, 0, 0, 0);
}

// async global->LDS, 16B per lane, LDS dest = uniform base + lane*16
__device__ __forceinline__ void gload16(const float* g, float* lds) {
    __builtin_amdgcn_global_load_lds(
        (const __attribute__((address_space(1))) void*)g,
        (__attribute__((address_space(3))) void*)lds,
        16, 0, 0);
}

// ---- kernel 0: weight prep (unchanged) --------------------------------------
__global__ void k_prep(const float* __restrict__ W0, const float* __restrict__ W1,
                       unsigned short* __restrict__ W0T, unsigned char* __restrict__ W1f8s) {
    int i = blockIdx.x * 256 + threadIdx.x;
    if (i < 8192) {                       // W0T[j][k] = W0[k][j]
        int j = i >> 6, k = i & 63;
        W0T[i] = f2bf(W0[k * NH + j]);
    } else if (i < 24576) {               // W1f8s swizzled: elem (j, c)
        int i2 = i - 8192;
        int j = i2 >> 7, c = i2 & 127;
        W1f8s[(j * 16 + ((c >> 3) ^ (j & 7))) * 8 + (c & 7)] = f2fp8(W1[c * NH + j]);
    }
}

// ---- kernel 1: fused MLP, counted-vmcnt pipeline ------------------------------
// r12 structure. FIX: Hs is written as unsigned* and read as long* -- distinct
// TBAA types, so LLVM may legally hoist the a2 ds_reads above the Hs ds_writes
// (source of the 180-216 absmax in r11/r12). A zero-cost compiler memory
// barrier between write and read forbids the reorder.
__global__ __launch_bounds__(256, 2) void k_mlp(
        const float* __restrict__ X,
        const unsigned short* __restrict__ W0T,
        const unsigned char* __restrict__ W1f8s,
        const float* __restrict__ b0, const float* __restrict__ b1,
        const float* __restrict__ W2, const float* __restrict__ b2p,
        float* __restrict__ rawOut, unsigned* __restrict__ mcodeOut) {
    __shared__ __align__(16) unsigned char sW1f[16384];    // 16 KB W1 fp8 frags (swizzled)
    __shared__ __align__(16) float sFeat[4][2048];         // 8 KB/wave feats f32 (src-swizzled)
    __shared__ __align__(16) unsigned char sHs[4][4096];   // 4 KB/wave fp8 Hs (dedicated)
    __shared__ float sB0[128];
    __shared__ float sB1W2[256];                           // [0..127]=b1, [128..255]=W2

    const int t = threadIdx.x, w = t >> 6, l = t & 63;
    const int l15 = l & 15, g = l >> 4;
    const int rx = l15 & 7;

    // stage W1 fp8 + biases (once per block)
    {
        const uint4* src = (const uint4*)W1f8s;
        uint4* dst = (uint4*)sW1f;
#pragma unroll
        for (int i = 0; i < 4; ++i) dst[i * 256 + t] = src[i * 256 + t];
    }
    if (t < 128) { sB0[t] = b0[t]; sB1W2[t] = b1[t]; sB1W2[128 + t] = W2[t]; }

    // loop-invariant W0 fragments in registers (32 VGPRs)
    short8 w0f[8][2];
#pragma unroll
    for (int n = 0; n < 8; ++n)
#pragma unroll
        for (int kk = 0; kk < 2; ++kk)
            w0f[n][kk] = *(const short8*)(W0T + (n * 16 + l15) * 64 + kk * 32 + g * 8);
    const float b2v = b2p[0];

    __syncthreads();   // only barrier: sW1f/sB0/sB1W2 ready

    float* fw = sFeat[w];
    unsigned char* hs = sHs[w];
    const size_t rowwave0 = (size_t)blockIdx.x * (TILES * TILE_ROWS) + w * 32;

    // per-lane gload source offsets (floats): row-in-chunk r4, slot sl, swizzled
    const int r4 = l >> 4, sl = l & 15;
    const int offE = r4 * LDX + ((sl ^ r4) << 2);
    const int offO = r4 * LDX + ((sl ^ (r4 + 4)) << 2);

    // prologue: issue tile-0 staging (8 x 1KB) + tile-0 meta
    {
        const float* gb = X + rowwave0 * LDX;
#pragma unroll
        for (int k = 0; k < 8; ++k)
            gload16(gb + k * 4 * LDX + ((k & 1) ? offO : offE), fw + k * 256);
    }
    float2 mt = make_float2(0.f, 0.f), mtN = make_float2(0.f, 0.f);
    if (l < 32) mt = *(const float2*)(X + (rowwave0 + l) * LDX + 64);

    for (int tau = 0; tau < TILES; ++tau) {
        const size_t rowb = rowwave0 + (size_t)tau * TILE_ROWS;

        // counted wait: feats+meta landed; previous tile's 3 stores may float
        if (tau == 0) asm volatile("s_waitcnt vmcnt(0)" ::: "memory");
        else         asm volatile("s_waitcnt vmcnt(3)" ::: "memory");
        __builtin_amdgcn_sched_barrier(0);

        // feats fragments from f32 LDS (swizzled slots), pack to bf16
        short8 bfr[2][2];
#pragma unroll
        for (int rg = 0; rg < 2; ++rg)
#pragma unroll
            for (int kk = 0; kk < 2; ++kk) {
                const int row = rg * 16 + l15;
                const int u0 = kk * 8 + 2 * g;
                const float* base = fw + row * 64;
                float4 fa = *(const float4*)(base + ((u0 ^ rx) << 2));
                float4 fb = *(const float4*)(base + (((u0 + 1) ^ rx) << 2));
                union { unsigned u[4]; short8 s; } tu;
                tu.u[0] = pack2(fa.x, fa.y); tu.u[1] = pack2(fa.z, fa.w);
                tu.u[2] = pack2(fb.x, fb.y); tu.u[3] = pack2(fb.z, fb.w);
                bfr[rg][kk] = tu.s;
            }

        // fw fully consumed -> issue next tile's staging NOW (full-tile overlap)
        asm volatile("s_waitcnt lgkmcnt(0)" ::: "memory");
        __builtin_amdgcn_sched_barrier(0);
        if (tau + 1 < TILES) {
            const float* gb = X + (rowb + TILE_ROWS) * LDX;
#pragma unroll
            for (int k = 0; k < 8; ++k)
                gload16(gb + k * 4 * LDX + ((k & 1) ? offO : offE), fw + k * 256);
            if (l < 32) mtN = *(const float2*)(X + (rowb + TILE_ROWS + l) * LDX + 64);
        }
        __builtin_amdgcn_sched_barrier(0);   // pin gload issues before compute

        // GEMM1 in two n-halves (acc liveness 32 regs); bias+relu -> fp8 Hs
#pragma unroll
        for (int nh = 0; nh < 2; ++nh) {
            f32x4 acc[4][2];
#pragma unroll
            for (int n4 = 0; n4 < 4; ++n4)
#pragma unroll
                for (int rg = 0; rg < 2; ++rg) acc[n4][rg] = (f32x4){0.f, 0.f, 0.f, 0.f};
#pragma unroll
            for (int n4 = 0; n4 < 4; ++n4) {
                const int n = nh * 4 + n4;
#pragma unroll
                for (int rg = 0; rg < 2; ++rg) {
                    acc[n4][rg] = mfma_bf16(w0f[n][0], bfr[rg][0], acc[n4][rg]);
                    acc[n4][rg] = mfma_bf16(w0f[n][1], bfr[rg][1], acc[n4][rg]);
                }
            }
#pragma unroll
            for (int n4 = 0; n4 < 4; ++n4) {
                const int n = nh * 4 + n4;
                const int c0 = n * 16 + g * 4;
                const float bv0 = sB0[c0], bv1 = sB0[c0+1], bv2 = sB0[c0+2], bv3 = sB0[c0+3];
                const int u = (2 * n + (g >> 1)) ^ rx;
#pragma unroll
                for (int rg = 0; rg < 2; ++rg) {
                    unsigned d0 = (unsigned)__builtin_amdgcn_cvt_pk_fp8_f32(
                        fmaxf(acc[n4][rg][0] + bv0, 0.f), fmaxf(acc[n4][rg][1] + bv1, 0.f), 0, false);
                    d0 = (unsigned)__builtin_amdgcn_cvt_pk_fp8_f32(
                        fmaxf(acc[n4][rg][2] + bv2, 0.f), fmaxf(acc[n4][rg][3] + bv3, 0.f), (int)d0, true);
                    *(unsigned*)(hs + ((rg * 16 + l15) * 16 + u) * 8 + (g & 1) * 4) = d0;
                }
            }
        }

        // THE FIX: compiler-level memory barrier. Hs writes above are unsigned*,
        // reads below are long* -> TBAA says no-alias -> without this barrier the
        // scheduler may hoist the reads above the writes (r11/r12 absmax ~200).
        asm volatile("" ::: "memory");

        // A2 fragments (fp8, swizzled) from dedicated Hs
        long a2[2][4];
#pragma unroll
        for (int rg = 0; rg < 2; ++rg)
#pragma unroll
            for (int kk = 0; kk < 4; ++kk)
                a2[rg][kk] = *(const long*)(hs + ((rg * 16 + l15) * 16 + ((kk * 4 + g) ^ rx)) * 8);

        // GEMM2 (fp8) + fused epilogue dot (overlaps in-flight staging)
        float rq[2][4] = {{0.f,0.f,0.f,0.f},{0.f,0.f,0.f,0.f}};
#pragma unroll
        for (int n = 0; n < 8; ++n) {
            f32x4 acc2[2] = {(f32x4){0.f,0.f,0.f,0.f}, (f32x4){0.f,0.f,0.f,0.f}};
            const unsigned char* wrow = sW1f + (n * 16 + l15) * 128;
#pragma unroll
            for (int kk = 0; kk < 4; ++kk) {
                long bb = *(const long*)(wrow + ((kk * 4 + g) ^ rx) * 8);
                acc2[0] = mfma_fp8(a2[0][kk], bb, acc2[0]);
                acc2[1] = mfma_fp8(a2[1][kk], bb, acc2[1]);
            }
            const float b1v = sB1W2[n * 16 + l15], w2v = sB1W2[128 + n * 16 + l15];
#pragma unroll
            for (int rg = 0; rg < 2; ++rg)
#pragma unroll
                for (int q = 0; q < 4; ++q)
                    rq[rg][q] += fmaxf(acc2[rg][q] + b1v, 0.f) * w2v;
        }

        // reduce over l15, store raw (2 float4) + per-lane mcode (1 dword)
#pragma unroll
        for (int off = 1; off < 16; off <<= 1)
#pragma unroll
            for (int rg = 0; rg < 2; ++rg)
#pragma unroll
                for (int q = 0; q < 4; ++q)
                    rq[rg][q] += __shfl_xor(rq[rg][q], off, 64);
        if (l15 == 0) {
#pragma unroll
            for (int rg = 0; rg < 2; ++rg) {
                const size_t m0 = rowb + rg * 16 + g * 4;
                *(float4*)(rawOut + m0) = make_float4(rq[rg][0] + b2v, rq[rg][1] + b2v,
                                                      rq[rg][2] + b2v, rq[rg][3] + b2v);
            }
        }
        if (l < 32) {
            const unsigned pmcu = ((unsigned)((int)mt.x + 1) << 1) | (mt.y > 0.f ? 1u : 0u);
            mcodeOut[rowb + l] = pmcu;
        }
        mt = mtN;
    }
}

// ---- kernel 2: fused per-batch-row stats + bias MLP + fair writeout ---------
__global__ __launch_bounds__(256) void k_bstats(
        const float* __restrict__ raw, const unsigned* __restrict__ mcode,
        const float* __restrict__ Wb0, const float* __restrict__ bb0,
        const float* __restrict__ Wb1, const float* __restrict__ bb1,
        float* __restrict__ out) {
    __shared__ unsigned scnt[512];
    __shared__ float    ssum[512];
    __shared__ unsigned smx[512];
    __shared__ float4   sstat[512];
    const int b = blockIdx.x, t = threadIdx.x;
    scnt[t] = 0u; ssum[t] = 0.f; smx[t] = 0u;
    scnt[t + 256] = 0u; ssum[t + 256] = 0.f; smx[t + 256] = 0u;
    __syncthreads();
    const int base = b * NC;
#pragma unroll 4
    for (int it = 0; it < 16; ++it) {
        int m = base + it * 256 + t;
        unsigned c = mcode[m];
        if ((c & 1u) && (c >> 1)) {
            int s = (int)(c >> 1) - 1;
            float r = raw[m];
            atomicAdd(&scnt[s], 1u);
            atomicAdd(&ssum[s], r);
            atomicMax(&smx[s], encf(r));
        }
    }
    __syncthreads();
#pragma unroll
    for (int k = 0; k < 2; ++k) {
        int s = t + k * 256;
        unsigned c = scnt[s];
        float smax = (c > 0) ? decf(smx[s]) : 0.f;
        float mean = ssum[s] / fmaxf((float)c, 1.f);
        float multi = (c > 1) ? 1.f : 0.f;
        float bias = 0.f;
        if (c > 1) {
            bias = bb1[0];
#pragma unroll
            for (int j = 0; j < 32; ++j) {
                float h = smax * Wb0[j] + mean * Wb0[32 + j] + (float)c * Wb0[64 + j] + bb0[j];
                bias += fmaxf(h, 0.f) * Wb1[j];
            }
        }
        sstat[s] = make_float4(smax, mean, bias, multi);
    }
    __syncthreads();
    const float4* raw4 = (const float4*)raw;
    const uint4*  mc4  = (const uint4*)mcode;
#pragma unroll
    for (int it = 0; it < 4; ++it) {
        int i = b * 1024 + it * 256 + t;
        float4 rv = raw4[i];
        uint4 mc = mc4[i];
        const float r[4]    = {rv.x, rv.y, rv.z, rv.w};
        const unsigned m[4] = {mc.x, mc.y, mc.z, mc.w};
        float fair[4], msk[4];
#pragma unroll
        for (int j = 0; j < 4; ++j) {
            msk[j] = (m[j] & 1u) ? 1.0f : 0.0f;
            float f;
            if (m[j] & 1u) {
                f = r[j];
                if (m[j] >> 1) {
                    float4 st = sstat[(int)(m[j] >> 1) - 1];
                    if (st.w > 0.5f) f = 1.5f * r[j] - st.y + 0.5f * st.x + st.z;
                }
            } else {
                f = NEGV;
            }
            fair[j] = f;
        }
        const size_t m0 = (size_t)i * 4;
        *(float4*)(out + m0) = make_float4(fair[0], fair[1], fair[2], fair[3]);
        *(float4*)(out + NELEM + m0) = make_float4(msk[0], msk[1], msk[2], msk[3]);
    }
}

// ---- launch ----------------------------------------------------------------
extern "C" void kernel_launch(void* const* d_in, const int* in_sizes, int n_in,
                              void* d_out, int out_size, void* d_ws, size_t ws_size,
                              hipStream_t stream) {
    const float* X   = (const float*)d_in[0];
    const float* W0  = (const float*)d_in[1];
    const float* b0  = (const float*)d_in[2];
    const float* W1  = (const float*)d_in[3];
    const float* b1  = (const float*)d_in[4];
    const float* W2  = (const float*)d_in[5];
    const float* b2  = (const float*)d_in[6];
    const float* Wb0 = (const float*)d_in[7];
    const float* bb0 = (const float*)d_in[8];
    const float* Wb1 = (const float*)d_in[9];
    const float* bb1 = (const float*)d_in[10];

    char* ws = (char*)d_ws;
    float*          raw      = (float*)(ws + 0);                 // 4 MB
    unsigned*       mcode    = (unsigned*)(ws + 4194304);        // 4 MB
    unsigned short* W0T      = (unsigned short*)(ws + 8388608);  // 16 KB
    unsigned char*  W1f8s    = (unsigned char*)(ws + 8404992);   // 16 KB

    k_prep<<<96, 256, 0, stream>>>(W0, W1, W0T, W1f8s);
    k_mlp<<<GRID_MLP, 256, 0, stream>>>(X, W0T, W1f8s, b0, b1, W2, b2, raw, mcode);
    k_bstats<<<NB, 256, 0, stream>>>(raw, mcode, Wb0, bb0, Wb1, bb1, (float*)d_out);
}

// Round 14
// 81.348 us; speedup vs baseline: 1.1231x; 1.1231x over previous
//
#include <hip/hip_runtime.h>
#include <hip/hip_bf16.h>

// Problem constants
#define NB   256
#define NC   4096
#define NG   512
#define NH   128
#define NELEM (NB*NC)            // 1048576
#define LDX  66                  // row stride of x_with_meta in floats
#define NEGV (-1000000000.0f)
#define TILES 16                 // iterations: 8 waves x 32 rows x 16 = 4096 rows/block

typedef __attribute__((ext_vector_type(8))) short short8;
typedef __attribute__((ext_vector_type(4))) float f32x4;

// truncating f32->bf16 pair pack
__device__ __forceinline__ unsigned pack2(float x, float y) {
    return (__float_as_uint(y) & 0xFFFF0000u) | (__float_as_uint(x) >> 16);
}
__device__ __forceinline__ unsigned short f2bf(float f) {   // RNE, off hot path
    unsigned u = __float_as_uint(f);
    return (unsigned short)((u + 0x7FFFu + ((u >> 16) & 1u)) >> 16);
}
__device__ __forceinline__ unsigned char f2fp8(float f) {   // e4m3, off hot path
    return (unsigned char)((unsigned)__builtin_amdgcn_cvt_pk_fp8_f32(f, 0.f, 0, false) & 0xFFu);
}
__device__ __forceinline__ unsigned encf(float f) {         // order-preserving f32->u32
    unsigned u = __float_as_uint(f);
    return (u & 0x80000000u) ? ~u : (u | 0x80000000u);
}
__device__ __forceinline__ float decf(unsigned u) {
    unsigned v = (u & 0x80000000u) ? (u ^ 0x80000000u) : ~u;
    return __uint_as_float(v);
}
__device__ __forceinline__ f32x4 mfma_bf16(short8 a, short8 b, f32x4 c) {
    return __builtin_amdgcn_mfma_f32_16x16x32_bf16(a, b, c, 0, 0, 0);
}
__device__ __forceinline__ f32x4 mfma_fp8(long a, long b, f32x4 c) {
    return __builtin_amdgcn_mfma_f32_16x16x32_fp8_fp8(a, b, c, 0, 0, 0);
}

// async global->LDS, 16B per lane, LDS dest = uniform base + lane*16
__device__ __forceinline__ void gload16(const float* g, float* lds) {
    __builtin_amdgcn_global_load_lds(
        (const __attribute__((address_space(1))) void*)g,
        (__attribute__((address_space(3))) void*)lds,
        16, 0, 0);
}

// ---- kernel 0: weight prep (unchanged) --------------------------------------
__global__ void k_prep(const float* __restrict__ W0, const float* __restrict__ W1,
                       unsigned short* __restrict__ W0T, unsigned char* __restrict__ W1f8s) {
    int i = blockIdx.x * 256 + threadIdx.x;
    if (i < 8192) {                       // W0T[j][k] = W0[k][j]
        int j = i >> 6, k = i & 63;
        W0T[i] = f2bf(W0[k * NH + j]);
    } else if (i < 24576) {               // W1f8s swizzled: elem (j, c)
        int i2 = i - 8192;
        int j = i2 >> 7, c = i2 & 127;
        W1f8s[(j * 16 + ((c >> 3) ^ (j & 7))) * 8 + (c & 7)] = f2fp8(W1[c * NH + j]);
    }
}

// ---- kernel 1: FULLY FUSED: MLP + segment stats + bias MLP + fair writeout ---
// One block (512 thr = 8 waves) per batch row b. Main loop = r13 k_mlp verbatim
// (per-wave, barrier-free, counted-vmcnt staging) except: tile stride 256 rows,
// raw/mcode stored to LDS, no global stores in loop (top wait = vmcnt(0)).
// Then: __syncthreads -> LDS segment reduce -> per-seg bias MLP -> fair writeout.
// LDS ~146 KB -> 1 block/CU, 8 waves/CU (same wave count as r13). Grid = 256.
__global__ __launch_bounds__(512, 2) void k_fused(
        const float* __restrict__ X,
        const unsigned short* __restrict__ W0T,
        const unsigned char* __restrict__ W1f8s,
        const float* __restrict__ b0, const float* __restrict__ b1,
        const float* __restrict__ W2, const float* __restrict__ b2p,
        const float* __restrict__ Wb0, const float* __restrict__ bb0,
        const float* __restrict__ Wb1, const float* __restrict__ bb1,
        float* __restrict__ out) {
    __shared__ __align__(16) unsigned char sW1f[16384];     // 16 KB W1 fp8 frags (swizzled)
    __shared__ __align__(16) float sFeat[8][2048];          // 8 KB/wave feats f32 (src-swizzled)
    __shared__ __align__(16) unsigned char sHs[8][4096];    // 4 KB/wave fp8 Hs (dedicated)
    __shared__ float sB0[128];
    __shared__ float sB1W2[256];                            // [0..127]=b1, [128..255]=W2
    __shared__ __align__(16) float sraw[4096];              // 16 KB raw (LDS only!)
    __shared__ unsigned short smc[4096];                    // 8 KB meta codes (LDS only!)
    __shared__ unsigned scnt[512];
    __shared__ float    ssum[512];
    __shared__ unsigned smx[512];
    __shared__ float    sdelta[512];
    __shared__ unsigned char smulti[512];

    const int t = threadIdx.x, w = t >> 6, l = t & 63;
    const int l15 = l & 15, g = l >> 4;
    const int rx = l15 & 7;
    const int b = blockIdx.x;

    // stage W1 fp8 + biases + init seg arrays (once per block)
    {
        const uint4* src = (const uint4*)W1f8s;
        uint4* dst = (uint4*)sW1f;
        dst[t] = src[t]; dst[512 + t] = src[512 + t];
    }
    if (t < 128) { sB0[t] = b0[t]; sB1W2[t] = b1[t]; sB1W2[128 + t] = W2[t]; }
    scnt[t] = 0u; ssum[t] = 0.f; smx[t] = 0u;

    // loop-invariant W0 fragments in registers (32 VGPRs)
    short8 w0f[8][2];
#pragma unroll
    for (int n = 0; n < 8; ++n)
#pragma unroll
        for (int kk = 0; kk < 2; ++kk)
            w0f[n][kk] = *(const short8*)(W0T + (n * 16 + l15) * 64 + kk * 32 + g * 8);
    const float b2v = b2p[0];

    __syncthreads();   // weights + seg-array init ready

    float* fw = sFeat[w];
    unsigned char* hs = sHs[w];
    const size_t rowwave0 = (size_t)b * NC + w * 32;
    const int lrow0 = w * 32;

    // per-lane gload source offsets (floats): row-in-chunk r4, slot sl, swizzled
    const int r4 = l >> 4, sl = l & 15;
    const int offE = r4 * LDX + ((sl ^ r4) << 2);
    const int offO = r4 * LDX + ((sl ^ (r4 + 4)) << 2);

    // prologue: issue tile-0 staging (8 x 1KB) + tile-0 meta
    {
        const float* gb = X + rowwave0 * LDX;
#pragma unroll
        for (int k = 0; k < 8; ++k)
            gload16(gb + k * 4 * LDX + ((k & 1) ? offO : offE), fw + k * 256);
    }
    float2 mt = make_float2(0.f, 0.f), mtN = make_float2(0.f, 0.f);
    if (l < 32) mt = *(const float2*)(X + (rowwave0 + l) * LDX + 64);

    for (int tau = 0; tau < TILES; ++tau) {
        const size_t rowb = rowwave0 + (size_t)tau * 256;   // 8 waves x 32 rows stride
        const int lrow = lrow0 + tau * 256;

        // only VMEM in flight are this tile's 8 gloads + meta load
        asm volatile("s_waitcnt vmcnt(0)" ::: "memory");
        __builtin_amdgcn_sched_barrier(0);

        // feats fragments from f32 LDS (swizzled slots), pack to bf16
        short8 bfr[2][2];
#pragma unroll
        for (int rg = 0; rg < 2; ++rg)
#pragma unroll
            for (int kk = 0; kk < 2; ++kk) {
                const int row = rg * 16 + l15;
                const int u0 = kk * 8 + 2 * g;
                const float* base = fw + row * 64;
                float4 fa = *(const float4*)(base + ((u0 ^ rx) << 2));
                float4 fb = *(const float4*)(base + (((u0 + 1) ^ rx) << 2));
                union { unsigned u[4]; short8 s; } tu;
                tu.u[0] = pack2(fa.x, fa.y); tu.u[1] = pack2(fa.z, fa.w);
                tu.u[2] = pack2(fb.x, fb.y); tu.u[3] = pack2(fb.z, fb.w);
                bfr[rg][kk] = tu.s;
            }

        // fw fully consumed -> issue next tile's staging NOW (full-tile overlap)
        asm volatile("s_waitcnt lgkmcnt(0)" ::: "memory");
        __builtin_amdgcn_sched_barrier(0);
        if (tau + 1 < TILES) {
            const float* gb = X + (rowb + 256) * LDX;
#pragma unroll
            for (int k = 0; k < 8; ++k)
                gload16(gb + k * 4 * LDX + ((k & 1) ? offO : offE), fw + k * 256);
            if (l < 32) mtN = *(const float2*)(X + (rowb + 256 + l) * LDX + 64);
        }
        __builtin_amdgcn_sched_barrier(0);   // pin gload issues before compute

        // GEMM1 in two n-halves (acc liveness 32 regs); bias+relu -> fp8 Hs
#pragma unroll
        for (int nh = 0; nh < 2; ++nh) {
            f32x4 acc[4][2];
#pragma unroll
            for (int n4 = 0; n4 < 4; ++n4)
#pragma unroll
                for (int rg = 0; rg < 2; ++rg) acc[n4][rg] = (f32x4){0.f, 0.f, 0.f, 0.f};
#pragma unroll
            for (int n4 = 0; n4 < 4; ++n4) {
                const int n = nh * 4 + n4;
#pragma unroll
                for (int rg = 0; rg < 2; ++rg) {
                    acc[n4][rg] = mfma_bf16(w0f[n][0], bfr[rg][0], acc[n4][rg]);
                    acc[n4][rg] = mfma_bf16(w0f[n][1], bfr[rg][1], acc[n4][rg]);
                }
            }
#pragma unroll
            for (int n4 = 0; n4 < 4; ++n4) {
                const int n = nh * 4 + n4;
                const int c0 = n * 16 + g * 4;
                const float bv0 = sB0[c0], bv1 = sB0[c0+1], bv2 = sB0[c0+2], bv3 = sB0[c0+3];
                const int u = (2 * n + (g >> 1)) ^ rx;
#pragma unroll
                for (int rg = 0; rg < 2; ++rg) {
                    unsigned d0 = (unsigned)__builtin_amdgcn_cvt_pk_fp8_f32(
                        fmaxf(acc[n4][rg][0] + bv0, 0.f), fmaxf(acc[n4][rg][1] + bv1, 0.f), 0, false);
                    d0 = (unsigned)__builtin_amdgcn_cvt_pk_fp8_f32(
                        fmaxf(acc[n4][rg][2] + bv2, 0.f), fmaxf(acc[n4][rg][3] + bv3, 0.f), (int)d0, true);
                    *(unsigned*)(hs + ((rg * 16 + l15) * 16 + u) * 8 + (g & 1) * 4) = d0;
                }
            }
        }

        // compiler memory barrier: Hs written as unsigned*, read as long* (TBAA
        // no-alias) -- without this the a2 reads may be hoisted above the writes.
        asm volatile("" ::: "memory");

        // A2 fragments (fp8, swizzled) from dedicated Hs
        long a2[2][4];
#pragma unroll
        for (int rg = 0; rg < 2; ++rg)
#pragma unroll
            for (int kk = 0; kk < 4; ++kk)
                a2[rg][kk] = *(const long*)(hs + ((rg * 16 + l15) * 16 + ((kk * 4 + g) ^ rx)) * 8);

        // GEMM2 (fp8) + fused epilogue dot (overlaps in-flight staging)
        float rq[2][4] = {{0.f,0.f,0.f,0.f},{0.f,0.f,0.f,0.f}};
#pragma unroll
        for (int n = 0; n < 8; ++n) {
            f32x4 acc2[2] = {(f32x4){0.f,0.f,0.f,0.f}, (f32x4){0.f,0.f,0.f,0.f}};
            const unsigned char* wrow = sW1f + (n * 16 + l15) * 128;
#pragma unroll
            for (int kk = 0; kk < 4; ++kk) {
                long bb = *(const long*)(wrow + ((kk * 4 + g) ^ rx) * 8);
                acc2[0] = mfma_fp8(a2[0][kk], bb, acc2[0]);
                acc2[1] = mfma_fp8(a2[1][kk], bb, acc2[1]);
            }
            const float b1v = sB1W2[n * 16 + l15], w2v = sB1W2[128 + n * 16 + l15];
#pragma unroll
            for (int rg = 0; rg < 2; ++rg)
#pragma unroll
                for (int q = 0; q < 4; ++q)
                    rq[rg][q] += fmaxf(acc2[rg][q] + b1v, 0.f) * w2v;
        }

        // reduce over l15, store raw + mcode to LDS (no global traffic)
#pragma unroll
        for (int off = 1; off < 16; off <<= 1)
#pragma unroll
            for (int rg = 0; rg < 2; ++rg)
#pragma unroll
                for (int q = 0; q < 4; ++q)
                    rq[rg][q] += __shfl_xor(rq[rg][q], off, 64);
        if (l15 == 0) {
#pragma unroll
            for (int rg = 0; rg < 2; ++rg) {
                const int lm0 = lrow + rg * 16 + g * 4;
                *(float4*)(sraw + lm0) = make_float4(rq[rg][0] + b2v, rq[rg][1] + b2v,
                                                     rq[rg][2] + b2v, rq[rg][3] + b2v);
            }
        }
        if (l < 32) {
            const unsigned pmcu = ((unsigned)((int)mt.x + 1) << 1) | (mt.y > 0.f ? 1u : 0u);
            smc[lrow + l] = (unsigned short)pmcu;
        }
        mt = mtN;
    }

    __syncthreads();   // all raw/mcode in LDS

    // ---- segment reduction (LDS atomics over 512 segs) ----
#pragma unroll
    for (int it = 0; it < 8; ++it) {
        int m = it * 512 + t;
        unsigned c = smc[m];
        if ((c & 1u) && (c >> 1)) {
            int s = (int)(c >> 1) - 1;
            float r = sraw[m];
            atomicAdd(&scnt[s], 1u);
            atomicAdd(&ssum[s], r);
            atomicMax(&smx[s], encf(r));
        }
    }
    __syncthreads();

    // ---- per-seg bias MLP (thread t owns seg t): delta = 0.5*max - mean + bias
    {
        unsigned c = scnt[t];
        float delta = 0.f; unsigned char multi = 0;
        if (c > 1) {
            float smaxv = decf(smx[t]);
            float mean = ssum[t] / (float)c;
            float bias = bb1[0];
#pragma unroll
            for (int j = 0; j < 32; ++j) {
                float h = smaxv * Wb0[j] + mean * Wb0[32 + j] + (float)c * Wb0[64 + j] + bb0[j];
                bias += fmaxf(h, 0.f) * Wb1[j];
            }
            delta = 0.5f * smaxv - mean + bias;
            multi = 1;
        }
        sdelta[t] = delta; smulti[t] = multi;
    }
    __syncthreads();

    // ---- fair/mask writeout (coalesced float4) ----
    const size_t gbase = (size_t)b * NC;
#pragma unroll
    for (int it = 0; it < 2; ++it) {
        int i = it * 512 + t;           // float4 group within row
        int m0 = i * 4;
        float4 rv = *(const float4*)(sraw + m0);
        const float r[4] = {rv.x, rv.y, rv.z, rv.w};
        float fair[4], msk[4];
#pragma unroll
        for (int j = 0; j < 4; ++j) {
            unsigned c = smc[m0 + j];
            msk[j] = (c & 1u) ? 1.0f : 0.0f;
            float f;
            if (c & 1u) {
                f = r[j];
                if (c >> 1) {
                    int s = (int)(c >> 1) - 1;
                    if (smulti[s]) f = 1.5f * r[j] + sdelta[s];
                }
            } else {
                f = NEGV;
            }
            fair[j] = f;
        }
        *(float4*)(out + gbase + m0) = make_float4(fair[0], fair[1], fair[2], fair[3]);
        *(float4*)(out + NELEM + gbase + m0) = make_float4(msk[0], msk[1], msk[2], msk[3]);
    }
}

// ---- launch ----------------------------------------------------------------
extern "C" void kernel_launch(void* const* d_in, const int* in_sizes, int n_in,
                              void* d_out, int out_size, void* d_ws, size_t ws_size,
                              hipStream_t stream) {
    const float* X   = (const float*)d_in[0];
    const float* W0  = (const float*)d_in[1];
    const float* b0  = (const float*)d_in[2];
    const float* W1  = (const float*)d_in[3];
    const float* b1  = (const float*)d_in[4];
    const float* W2  = (const float*)d_in[5];
    const float* b2  = (const float*)d_in[6];
    const float* Wb0 = (const float*)d_in[7];
    const float* bb0 = (const float*)d_in[8];
    const float* Wb1 = (const float*)d_in[9];
    const float* bb1 = (const float*)d_in[10];

    char* ws = (char*)d_ws;
    unsigned short* W0T   = (unsigned short*)(ws + 0);       // 16 KB
    unsigned char*  W1f8s = (unsigned char*)(ws + 16384);    // 16 KB

    k_prep<<<96, 256, 0, stream>>>(W0, W1, W0T, W1f8s);
    k_fused<<<NB, 512, 0, stream>>>(X, W0T, W1f8s, b0, b1, W2, b2,
                                    Wb0, bb0, Wb1, bb1, (float*)d_out);
}

// Round 15
// 76.019 us; speedup vs baseline: 1.2018x; 1.0701x over previous
//
#include <hip/hip_runtime.h>
#include <hip/hip_bf16.h>

// Problem constants
#define NB   256
#define NC   4096
#define NG   512
#define NH   128
#define NELEM (NB*NC)            // 1048576
#define LDX  66                  // row stride of x_with_meta in floats
#define NEGV (-1000000000.0f)
#define TILES 16                 // iterations: 8 waves x 32 rows x 16 = 4096 rows/block

typedef __attribute__((ext_vector_type(8))) short short8;
typedef __attribute__((ext_vector_type(4))) float f32x4;

// truncating f32->bf16 pair pack
__device__ __forceinline__ unsigned pack2(float x, float y) {
    return (__float_as_uint(y) & 0xFFFF0000u) | (__float_as_uint(x) >> 16);
}
__device__ __forceinline__ unsigned short f2bf(float f) {   // RNE, weights only
    unsigned u = __float_as_uint(f);
    return (unsigned short)((u + 0x7FFFu + ((u >> 16) & 1u)) >> 16);
}
__device__ __forceinline__ unsigned encf(float f) {         // order-preserving f32->u32
    unsigned u = __float_as_uint(f);
    return (u & 0x80000000u) ? ~u : (u | 0x80000000u);
}
__device__ __forceinline__ float decf(unsigned u) {
    unsigned v = (u & 0x80000000u) ? (u ^ 0x80000000u) : ~u;
    return __uint_as_float(v);
}
__device__ __forceinline__ f32x4 mfma_bf16(short8 a, short8 b, f32x4 c) {
    return __builtin_amdgcn_mfma_f32_16x16x32_bf16(a, b, c, 0, 0, 0);
}
__device__ __forceinline__ f32x4 mfma_fp8(long a, long b, f32x4 c) {
    return __builtin_amdgcn_mfma_f32_16x16x32_fp8_fp8(a, b, c, 0, 0, 0);
}

// async global->LDS, 16B per lane, LDS dest = uniform base + lane*16
__device__ __forceinline__ void gload16(const float* g, float* lds) {
    __builtin_amdgcn_global_load_lds(
        (const __attribute__((address_space(1))) void*)g,
        (__attribute__((address_space(3))) void*)lds,
        16, 0, 0);
}

// ---- single kernel: weight prep + MLP + segment stats + bias MLP + writeout --
// One block (512 thr = 8 waves) per batch row. Prologue converts W0->bf16
// (into sraw scratch, dead until tile-0 epilogue) and W1->fp8-swizzled (sW1f)
// in-block -- no k_prep dispatch, no weight global round-trip. Tile-0 feats
// gloads issue at kernel entry so cold HBM latency overlaps the conversion.
// Main loop + epilogue identical to r14 (absmax 0.21875 verified).
__global__ __launch_bounds__(512, 2) void k_fused(
        const float* __restrict__ X,
        const float* __restrict__ W0, const float* __restrict__ W1,
        const float* __restrict__ b0, const float* __restrict__ b1,
        const float* __restrict__ W2, const float* __restrict__ b2p,
        const float* __restrict__ Wb0, const float* __restrict__ bb0,
        const float* __restrict__ Wb1, const float* __restrict__ bb1,
        float* __restrict__ out) {
    __shared__ __align__(16) unsigned char sW1f[16384];     // 16 KB W1 fp8 frags (swizzled)
    __shared__ __align__(16) float sFeat[8][2048];          // 8 KB/wave feats f32 (src-swizzled)
    __shared__ __align__(16) unsigned char sHs[8][4096];    // 4 KB/wave fp8 Hs (dedicated)
    __shared__ float sB0[128];
    __shared__ float sB1W2[256];                            // [0..127]=b1, [128..255]=W2
    __shared__ __align__(16) float sraw[4096];              // 16 KB: W0T scratch, then raw
    __shared__ unsigned short smc[4096];                    // 8 KB meta codes (LDS only)
    __shared__ unsigned scnt[512];
    __shared__ float    ssum[512];
    __shared__ unsigned smx[512];
    __shared__ float    sdelta[512];
    __shared__ unsigned char smulti[512];

    const int t = threadIdx.x, w = t >> 6, l = t & 63;
    const int l15 = l & 15, g = l >> 4;
    const int rx = l15 & 7;
    const int b = blockIdx.x;

    float* fw = sFeat[w];
    unsigned char* hs = sHs[w];
    const size_t rowwave0 = (size_t)b * NC + w * 32;
    const int lrow0 = w * 32;

    // per-lane gload source offsets (floats): row-in-chunk r4, slot sl, swizzled
    const int r4 = l >> 4, sl = l & 15;
    const int offE = r4 * LDX + ((sl ^ r4) << 2);
    const int offO = r4 * LDX + ((sl ^ (r4 + 4)) << 2);

    // ---- FIRST: issue tile-0 staging + meta (overlaps weight conversion) ----
    {
        const float* gb = X + rowwave0 * LDX;
#pragma unroll
        for (int k = 0; k < 8; ++k)
            gload16(gb + k * 4 * LDX + ((k & 1) ? offO : offE), fw + k * 256);
    }
    float2 mt = make_float2(0.f, 0.f), mtN = make_float2(0.f, 0.f);
    if (l < 32) mt = *(const float2*)(X + (rowwave0 + l) * LDX + 64);

    // ---- in-block weight prep ----
    // W0 -> bf16 W0T layout [j][k] into sraw scratch (16 KB, dead until tile-0 epi)
    unsigned short* sW0s = (unsigned short*)sraw;
    {
        const int j = t & 127, kq = t >> 7;                 // k-range [kq*16, kq*16+16)
        unsigned pk[8];
#pragma unroll
        for (int kk = 0; kk < 16; kk += 2) {
            float v0 = W0[(kq * 16 + kk)     * NH + j];
            float v1 = W0[(kq * 16 + kk + 1) * NH + j];
            pk[kk >> 1] = (unsigned)f2bf(v0) | ((unsigned)f2bf(v1) << 16);
        }
        unsigned short* dst = sW0s + j * 64 + kq * 16;
        ((uint4*)dst)[0] = make_uint4(pk[0], pk[1], pk[2], pk[3]);
        ((uint4*)dst)[1] = make_uint4(pk[4], pk[5], pk[6], pk[7]);
    }
    // W1 -> fp8 e4m3, unit-swizzled (u' = u ^ (j&7)), directly into sW1f
#pragma unroll
    for (int it = 0; it < 4; ++it) {
        const int j = t & 127, u = (t >> 7) + it * 4;
        float v[8];
#pragma unroll
        for (int d = 0; d < 8; ++d) v[d] = W1[(u * 8 + d) * NH + j];
        unsigned lo = (unsigned)__builtin_amdgcn_cvt_pk_fp8_f32(v[0], v[1], 0, false);
        lo = (unsigned)__builtin_amdgcn_cvt_pk_fp8_f32(v[2], v[3], (int)lo, true);
        unsigned hi = (unsigned)__builtin_amdgcn_cvt_pk_fp8_f32(v[4], v[5], 0, false);
        hi = (unsigned)__builtin_amdgcn_cvt_pk_fp8_f32(v[6], v[7], (int)hi, true);
        *(uint2*)(sW1f + (j * 16 + (u ^ (j & 7))) * 8) = make_uint2(lo, hi);
    }
    if (t < 128) { sB0[t] = b0[t]; sB1W2[t] = b1[t]; sB1W2[128 + t] = W2[t]; }
    scnt[t] = 0u; ssum[t] = 0.f; smx[t] = 0u;
    const float b2v = b2p[0];

    __syncthreads();   // conversions + biases + seg-init visible

    // loop-invariant W0 fragments from LDS scratch (32 VGPRs)
    short8 w0f[8][2];
#pragma unroll
    for (int n = 0; n < 8; ++n)
#pragma unroll
        for (int kk = 0; kk < 2; ++kk)
            w0f[n][kk] = *(const short8*)(sW0s + (n * 16 + l15) * 64 + kk * 32 + g * 8);

    __syncthreads();   // all w0f reads done before sraw is overwritten by raws

    for (int tau = 0; tau < TILES; ++tau) {
        const size_t rowb = rowwave0 + (size_t)tau * 256;   // 8 waves x 32 rows stride
        const int lrow = lrow0 + tau * 256;

        // only VMEM in flight are this tile's 8 gloads + meta load
        asm volatile("s_waitcnt vmcnt(0)" ::: "memory");
        __builtin_amdgcn_sched_barrier(0);

        // feats fragments from f32 LDS (swizzled slots), pack to bf16
        short8 bfr[2][2];
#pragma unroll
        for (int rg = 0; rg < 2; ++rg)
#pragma unroll
            for (int kk = 0; kk < 2; ++kk) {
                const int row = rg * 16 + l15;
                const int u0 = kk * 8 + 2 * g;
                const float* base = fw + row * 64;
                float4 fa = *(const float4*)(base + ((u0 ^ rx) << 2));
                float4 fb = *(const float4*)(base + (((u0 + 1) ^ rx) << 2));
                union { unsigned u[4]; short8 s; } tu;
                tu.u[0] = pack2(fa.x, fa.y); tu.u[1] = pack2(fa.z, fa.w);
                tu.u[2] = pack2(fb.x, fb.y); tu.u[3] = pack2(fb.z, fb.w);
                bfr[rg][kk] = tu.s;
            }

        // fw fully consumed -> issue next tile's staging NOW (full-tile overlap)
        asm volatile("s_waitcnt lgkmcnt(0)" ::: "memory");
        __builtin_amdgcn_sched_barrier(0);
        if (tau + 1 < TILES) {
            const float* gb = X + (rowb + 256) * LDX;
#pragma unroll
            for (int k = 0; k < 8; ++k)
                gload16(gb + k * 4 * LDX + ((k & 1) ? offO : offE), fw + k * 256);
            if (l < 32) mtN = *(const float2*)(X + (rowb + 256 + l) * LDX + 64);
        }
        __builtin_amdgcn_sched_barrier(0);   // pin gload issues before compute

        // GEMM1 in two n-halves (acc liveness 32 regs); bias+relu -> fp8 Hs
#pragma unroll
        for (int nh = 0; nh < 2; ++nh) {
            f32x4 acc[4][2];
#pragma unroll
            for (int n4 = 0; n4 < 4; ++n4)
#pragma unroll
                for (int rg = 0; rg < 2; ++rg) acc[n4][rg] = (f32x4){0.f, 0.f, 0.f, 0.f};
#pragma unroll
            for (int n4 = 0; n4 < 4; ++n4) {
                const int n = nh * 4 + n4;
#pragma unroll
                for (int rg = 0; rg < 2; ++rg) {
                    acc[n4][rg] = mfma_bf16(w0f[n][0], bfr[rg][0], acc[n4][rg]);
                    acc[n4][rg] = mfma_bf16(w0f[n][1], bfr[rg][1], acc[n4][rg]);
                }
            }
#pragma unroll
            for (int n4 = 0; n4 < 4; ++n4) {
                const int n = nh * 4 + n4;
                const int c0 = n * 16 + g * 4;
                const float bv0 = sB0[c0], bv1 = sB0[c0+1], bv2 = sB0[c0+2], bv3 = sB0[c0+3];
                const int u = (2 * n + (g >> 1)) ^ rx;
#pragma unroll
                for (int rg = 0; rg < 2; ++rg) {
                    unsigned d0 = (unsigned)__builtin_amdgcn_cvt_pk_fp8_f32(
                        fmaxf(acc[n4][rg][0] + bv0, 0.f), fmaxf(acc[n4][rg][1] + bv1, 0.f), 0, false);
                    d0 = (unsigned)__builtin_amdgcn_cvt_pk_fp8_f32(
                        fmaxf(acc[n4][rg][2] + bv2, 0.f), fmaxf(acc[n4][rg][3] + bv3, 0.f), (int)d0, true);
                    *(unsigned*)(hs + ((rg * 16 + l15) * 16 + u) * 8 + (g & 1) * 4) = d0;
                }
            }
        }

        // compiler memory barrier: Hs written as unsigned*, read as long* (TBAA
        // no-alias) -- without this the a2 reads may be hoisted above the writes.
        asm volatile("" ::: "memory");

        // A2 fragments (fp8, swizzled) from dedicated Hs
        long a2[2][4];
#pragma unroll
        for (int rg = 0; rg < 2; ++rg)
#pragma unroll
            for (int kk = 0; kk < 4; ++kk)
                a2[rg][kk] = *(const long*)(hs + ((rg * 16 + l15) * 16 + ((kk * 4 + g) ^ rx)) * 8);

        // GEMM2 (fp8) + fused epilogue dot (overlaps in-flight staging)
        float rq[2][4] = {{0.f,0.f,0.f,0.f},{0.f,0.f,0.f,0.f}};
#pragma unroll
        for (int n = 0; n < 8; ++n) {
            f32x4 acc2[2] = {(f32x4){0.f,0.f,0.f,0.f}, (f32x4){0.f,0.f,0.f,0.f}};
            const unsigned char* wrow = sW1f + (n * 16 + l15) * 128;
#pragma unroll
            for (int kk = 0; kk < 4; ++kk) {
                long bb = *(const long*)(wrow + ((kk * 4 + g) ^ rx) * 8);
                acc2[0] = mfma_fp8(a2[0][kk], bb, acc2[0]);
                acc2[1] = mfma_fp8(a2[1][kk], bb, acc2[1]);
            }
            const float b1v = sB1W2[n * 16 + l15], w2v = sB1W2[128 + n * 16 + l15];
#pragma unroll
            for (int rg = 0; rg < 2; ++rg)
#pragma unroll
                for (int q = 0; q < 4; ++q)
                    rq[rg][q] += fmaxf(acc2[rg][q] + b1v, 0.f) * w2v;
        }

        // reduce over l15, store raw + mcode to LDS (no global traffic)
#pragma unroll
        for (int off = 1; off < 16; off <<= 1)
#pragma unroll
            for (int rg = 0; rg < 2; ++rg)
#pragma unroll
                for (int q = 0; q < 4; ++q)
                    rq[rg][q] += __shfl_xor(rq[rg][q], off, 64);
        if (l15 == 0) {
#pragma unroll
            for (int rg = 0; rg < 2; ++rg) {
                const int lm0 = lrow + rg * 16 + g * 4;
                *(float4*)(sraw + lm0) = make_float4(rq[rg][0] + b2v, rq[rg][1] + b2v,
                                                     rq[rg][2] + b2v, rq[rg][3] + b2v);
            }
        }
        if (l < 32) {
            const unsigned pmcu = ((unsigned)((int)mt.x + 1) << 1) | (mt.y > 0.f ? 1u : 0u);
            smc[lrow + l] = (unsigned short)pmcu;
        }
        mt = mtN;
    }

    __syncthreads();   // all raw/mcode in LDS

    // ---- segment reduction (LDS atomics over 512 segs) ----
#pragma unroll
    for (int it = 0; it < 8; ++it) {
        int m = it * 512 + t;
        unsigned c = smc[m];
        if ((c & 1u) && (c >> 1)) {
            int s = (int)(c >> 1) - 1;
            float r = sraw[m];
            atomicAdd(&scnt[s], 1u);
            atomicAdd(&ssum[s], r);
            atomicMax(&smx[s], encf(r));
        }
    }
    __syncthreads();

    // ---- per-seg bias MLP (thread t owns seg t): delta = 0.5*max - mean + bias
    {
        unsigned c = scnt[t];
        float delta = 0.f; unsigned char multi = 0;
        if (c > 1) {
            float smaxv = decf(smx[t]);
            float mean = ssum[t] / (float)c;
            float bias = bb1[0];
#pragma unroll
            for (int j = 0; j < 32; ++j) {
                float h = smaxv * Wb0[j] + mean * Wb0[32 + j] + (float)c * Wb0[64 + j] + bb0[j];
                bias += fmaxf(h, 0.f) * Wb1[j];
            }
            delta = 0.5f * smaxv - mean + bias;
            multi = 1;
        }
        sdelta[t] = delta; smulti[t] = multi;
    }
    __syncthreads();

    // ---- fair/mask writeout (coalesced float4) ----
    const size_t gbase = (size_t)b * NC;
#pragma unroll
    for (int it = 0; it < 2; ++it) {
        int i = it * 512 + t;           // float4 group within row
        int m0 = i * 4;
        float4 rv = *(const float4*)(sraw + m0);
        const float r[4] = {rv.x, rv.y, rv.z, rv.w};
        float fair[4], msk[4];
#pragma unroll
        for (int j = 0; j < 4; ++j) {
            unsigned c = smc[m0 + j];
            msk[j] = (c & 1u) ? 1.0f : 0.0f;
            float f;
            if (c & 1u) {
                f = r[j];
                if (c >> 1) {
                    int s = (int)(c >> 1) - 1;
                    if (smulti[s]) f = 1.5f * r[j] + sdelta[s];
                }
            } else {
                f = NEGV;
            }
            fair[j] = f;
        }
        *(float4*)(out + gbase + m0) = make_float4(fair[0], fair[1], fair[2], fair[3]);
        *(float4*)(out + NELEM + gbase + m0) = make_float4(msk[0], msk[1], msk[2], msk[3]);
    }
}

// ---- launch ----------------------------------------------------------------
extern "C" void kernel_launch(void* const* d_in, const int* in_sizes, int n_in,
                              void* d_out, int out_size, void* d_ws, size_t ws_size,
                              hipStream_t stream) {
    const float* X   = (const float*)d_in[0];
    const float* W0  = (const float*)d_in[1];
    const float* b0  = (const float*)d_in[2];
    const float* W1  = (const float*)d_in[3];
    const float* b1  = (const float*)d_in[4];
    const float* W2  = (const float*)d_in[5];
    const float* b2  = (const float*)d_in[6];
    const float* Wb0 = (const float*)d_in[7];
    const float* bb0 = (const float*)d_in[8];
    const float* Wb1 = (const float*)d_in[9];
    const float* bb1 = (const float*)d_in[10];

    k_fused<<<NB, 512, 0, stream>>>(X, W0, W1, b0, b1, W2, b2,
                                    Wb0, bb0, Wb1, bb1, (float*)d_out);
}